// Round 21
// baseline (80.256 us; speedup 1.0000x reference)
//
#include <hip/hip_runtime.h>
#include <hip/hip_bf16.h>
#include <stdint.h>

#define B_N 4096
#define V_N 2
#define D_N 1024
#define EPS 1e-8f
#define NT 32                // 4096/128 tiles per dim
#define NTRI (NT*(NT+1)/2)   // 528 = 8*66 -> clean XCD chunking
#define NSTEP 8              // K-steps of BK=128 fp8

typedef __attribute__((ext_vector_type(4))) float f32x4;
typedef __attribute__((ext_vector_type(2))) long long ll2;
typedef __attribute__((ext_vector_type(4))) unsigned int u32x4;

__device__ __forceinline__ unsigned int f2mono(float f) {
    unsigned int u = __float_as_uint(f);
    return (u & 0x80000000u) ? ~u : (u | 0x80000000u);
}

__device__ __forceinline__ float mono2f(unsigned int m) {
    unsigned int u = (m & 0x80000000u) ? (m ^ 0x80000000u) : ~m;
    return __uint_as_float(u);
}

__device__ __forceinline__ unsigned long long shfl_xor_u64(unsigned long long v, int m) {
    unsigned int lo = (unsigned int)v, hi = (unsigned int)(v >> 32);
    lo = __shfl_xor(lo, m, 64);
    hi = __shfl_xor(hi, m, 64);
    return ((unsigned long long)hi << 32) | lo;
}

// -------- Kernel 1: L2-normalize, emit OCP fp8 e4m3 (V,B,D) ---------------
// Also zeroes this block's rowmax slot (replaces the memset dispatch).
__global__ __launch_bounds__(256) void knorm(const float* __restrict__ x,
                                             unsigned int* __restrict__ xq,
                                             unsigned long long* __restrict__ rowmax) {
    int r = blockIdx.x;            // r = b*V + v  (input rows are contiguous)
    int b = r >> 1, v = r & 1;
    if (threadIdx.x == 0) rowmax[r] = 0ull;
    const float* row = x + (size_t)r * D_N;
    int t = threadIdx.x;
    float4 val = reinterpret_cast<const float4*>(row)[t];
    float ss = val.x * val.x + val.y * val.y + val.z * val.z + val.w * val.w;
    #pragma unroll
    for (int s = 32; s > 0; s >>= 1) ss += __shfl_xor(ss, s, 64);
    __shared__ float wsum[4];
    if ((t & 63) == 0) wsum[t >> 6] = ss;
    __syncthreads();
    float tot = wsum[0] + wsum[1] + wsum[2] + wsum[3];
    float rn = 1.0f / sqrtf(tot + EPS);
    int pk = 0;
    pk = __builtin_amdgcn_cvt_pk_fp8_f32(val.x * rn, val.y * rn, pk, false);
    pk = __builtin_amdgcn_cvt_pk_fp8_f32(val.z * rn, val.w * rn, pk, true);
    xq[((size_t)v * B_N + b) * 256 + t] = (unsigned int)pk;
}

// ------- Kernel 2: per-view X·X^T, row-wise argmax, fp8 MFMA ---------------
// r19 base (BK=128, single 32 KB LDS buffer, 4 blocks/CU, 8 windows) +
// T14 async-STAGE split: tile t+1 is loaded global->REGISTERS before
// COMPUTE(t) (the ~800-cyc transfer flies under the ~1300-cyc compute);
// after the post-compute barrier: vmcnt(0) (already satisfied) ->
// 8x ds_write_b128 -> lgkmcnt(0) -> barrier.  LDS stays 32 KB so the
// co-residency that r20 lost (64 KB dbuf -> 2 blk/CU) is preserved.
// Staging regs: 8 x dwordx4 = 32 VGPR; total ~120-128 -> 4 waves/SIMD.
// Swizzle f(row)=row&7 (r19, PMC 0 conflicts); ds_writes lane-contiguous.
__global__ __launch_bounds__(256, 4) void kargmax(const unsigned char* __restrict__ xq,
                                                  unsigned long long* __restrict__ rowmax) {
    __shared__ unsigned char lA[16384];   // 128 rows x 128 B
    __shared__ unsigned char lB[16384];
    const int v = blockIdx.y;
    // T1: chunked XCD swizzle (bijective: 528 = 8*66)
    const int bx = (blockIdx.x & 7) * (NTRI / 8) + (blockIdx.x >> 3);
    int ti = (int)((sqrtf(8.f * (float)bx + 1.f) - 1.f) * 0.5f);
    while ((ti + 1) * (ti + 2) / 2 <= bx) ti++;
    while (ti * (ti + 1) / 2 > bx) ti--;
    const int tj = bx - ti * (ti + 1) / 2;
    const int i0 = ti * 128;
    const int j0 = tj * 128;
    const bool diag = (ti == tj);
    const unsigned char* Xv = xq + (size_t)v * B_N * D_N;

    const int tid = threadIdx.x;
    const int wid = tid >> 6, lane = tid & 63;
    const int wr = wid >> 1, wc = wid & 1;

    f32x4 acc[4][4];
    #pragma unroll
    for (int m = 0; m < 4; m++)
        #pragma unroll
        for (int n = 0; n < 4; n++) acc[m][n] = (f32x4){0.f, 0.f, 0.f, 0.f};

    // Write side: chunk k covers rows wid*32 + k*8 + (l>>3), physical 16B
    // slot l&7; source chunk = (l&7) ^ f(row), f(row) = row&7 = (l>>3).
    const int csw = ((lane & 7) ^ (lane >> 3)) * 16;
    const unsigned char* pA = Xv + (size_t)(i0 + wid * 32 + (lane >> 3)) * D_N + csw;
    const unsigned char* pB = Xv + (size_t)(j0 + wid * 32 + (lane >> 3)) * D_N + csw;
    // LDS dest for this lane (same bytes gload_lds would write: dst+lane*16)
    unsigned char* dA = lA + wid * 4096 + lane * 16;
    unsigned char* dB = lB + wid * 4096 + lane * 16;

    // Read side: round h, group g = lane>>4 reads logical slot h*4+g of row
    // (row%16 = lane&15): physical = (h*4+g) ^ (row&7).
    const int rs0 = (((lane >> 4) ^ (lane & 7))) * 16;
    const int rs1 = rs0 ^ 64;

    u32x4 ra[4], rb[4];

    // issue tile t's 8 loads into registers (HBM/L2 latency hides under
    // whatever compute follows before WRITE_LDS)
#define STAGE_LOAD(t) do {                                                     \
    const unsigned char* _a = pA + (t) * 128;                                  \
    const unsigned char* _b = pB + (t) * 128;                                  \
    _Pragma("unroll")                                                          \
    for (int k = 0; k < 4; k++) {                                              \
        ra[k] = *reinterpret_cast<const u32x4*>(_a + k * 8192);                \
        rb[k] = *reinterpret_cast<const u32x4*>(_b + k * 8192);                \
    }                                                                          \
} while (0)

    // vmcnt(0) then regs -> LDS, then lgkm drain (writes visible at barrier)
#define STAGE_WRITE do {                                                       \
    asm volatile("s_waitcnt vmcnt(0)" ::: "memory");                           \
    _Pragma("unroll")                                                          \
    for (int k = 0; k < 4; k++) {                                              \
        *reinterpret_cast<u32x4*>(dA + k * 1024) = ra[k];                      \
        *reinterpret_cast<u32x4*>(dB + k * 1024) = rb[k];                      \
    }                                                                          \
    asm volatile("s_waitcnt lgkmcnt(0)" ::: "memory");                         \
} while (0)

#define CROUND(rs) do {                                                        \
    ll2 a[4], b[4];                                                            \
    _Pragma("unroll")                                                          \
    for (int m = 0; m < 4; m++)                                                \
        a[m] = *reinterpret_cast<const ll2*>(                                  \
            lA + (wr * 64 + m * 16 + (lane & 15)) * 128 + (rs));               \
    _Pragma("unroll")                                                          \
    for (int n = 0; n < 4; n++)                                                \
        b[n] = *reinterpret_cast<const ll2*>(                                  \
            lB + (wc * 64 + n * 16 + (lane & 15)) * 128 + (rs));               \
    __builtin_amdgcn_s_setprio(1);                                             \
    _Pragma("unroll")                                                          \
    for (int m = 0; m < 4; m++)                                                \
        _Pragma("unroll")                                                      \
        for (int n = 0; n < 4; n++) {                                          \
            acc[m][n] = __builtin_amdgcn_mfma_f32_16x16x32_fp8_fp8(            \
                a[m][0], b[n][0], acc[m][n], 0, 0, 0);                         \
            acc[m][n] = __builtin_amdgcn_mfma_f32_16x16x32_fp8_fp8(            \
                a[m][1], b[n][1], acc[m][n], 0, 0, 0);                         \
        }                                                                      \
    __builtin_amdgcn_s_setprio(0);                                             \
} while (0)

#define COMPUTE do { CROUND(rs0); CROUND(rs1); } while (0)

    // ---- Prologue: tile 0 ----
    STAGE_LOAD(0);
    STAGE_WRITE;
    __builtin_amdgcn_s_barrier();
    // ---- Main loop: t = 0..6 ----
    #pragma unroll 1
    for (int t = 0; t < NSTEP - 1; ++t) {
        STAGE_LOAD(t + 1);      // loads fly under COMPUTE
        COMPUTE;                // tile t
        __builtin_amdgcn_s_barrier();   // all LDS reads of tile t retired
        STAGE_WRITE;            // vmcnt(0) satisfied; regs -> LDS
        __builtin_amdgcn_s_barrier();   // tile t+1 visible to all waves
    }
    COMPUTE;                    // tile 7

    // ---- Epilogue A: row side (rows i0.., cols j0..) ----
    // C/D layout: col = lane&15, row = (lane>>4)*4 + reg  [m89/m91-verified]
    #pragma unroll
    for (int m = 0; m < 4; m++) {
        int rbase = i0 + wr * 64 + m * 16;
        #pragma unroll
        for (int j = 0; j < 4; j++) {
            int grow = rbase + (lane >> 4) * 4 + j;
            unsigned long long best = 0ull;
            #pragma unroll
            for (int n = 0; n < 4; n++) {
                int gcol = j0 + wc * 64 + n * 16 + (lane & 15);
                float vdot = acc[m][n][j];
                unsigned long long p = (grow == gcol)
                    ? 0ull
                    : ((unsigned long long)f2mono(vdot) << 32) | (unsigned int)(~(unsigned int)gcol);
                best = p > best ? p : best;
            }
            #pragma unroll
            for (int s = 1; s < 16; s <<= 1) {
                unsigned long long o = shfl_xor_u64(best, s);
                best = o > best ? o : best;
            }
            if ((lane & 15) == 0)
                atomicMax(&rowmax[(size_t)v * B_N + grow], best);
        }
    }

    // ---- Epilogue B: transposed side (rows j0.., cols i0..), off-diag only ----
    if (!diag) {
        #pragma unroll
        for (int n = 0; n < 4; n++) {
            int growT = j0 + wc * 64 + n * 16 + (lane & 15);   // C column = transposed row
            unsigned long long best = 0ull;
            #pragma unroll
            for (int m = 0; m < 4; m++) {
                int ibase = i0 + wr * 64 + m * 16 + (lane >> 4) * 4;
                #pragma unroll
                for (int j = 0; j < 4; j++) {
                    int gi = ibase + j;                        // C row = transposed col
                    float vdot = acc[m][n][j];
                    unsigned long long p =
                        ((unsigned long long)f2mono(vdot) << 32) | (unsigned int)(~(unsigned int)gi);
                    best = p > best ? p : best;
                }
            }
            #pragma unroll
            for (int s = 16; s < 64; s <<= 1) {
                unsigned long long o = shfl_xor_u64(best, s);
                best = o > best ? o : best;
            }
            if (lane < 16)
                atomicMax(&rowmax[(size_t)v * B_N + growT], best);
        }
    }
#undef STAGE_LOAD
#undef STAGE_WRITE
#undef CROUND
#undef COMPUTE
}

// --- Kernel 3: decode loss directly from packed keys, reduce to scalar -----
// Key = (f2mono(dot) << 32) | ~col ; rows are unit-norm, dist = sqrt(2-2*dot).
__global__ __launch_bounds__(1024) void kloss(const unsigned long long* __restrict__ rowmax,
                                              float* __restrict__ out) {
    int t = threadIdx.x;
    float acc = 0.f;
    #pragma unroll
    for (int i = t; i < V_N * B_N; i += 1024) {
        unsigned long long k = rowmax[i];
        float dot = mono2f((unsigned int)(k >> 32));
        float d2 = fmaxf(2.0f - 2.0f * dot, 0.0f);
        acc += -logf(sqrtf(d2) + EPS);
    }
    __shared__ float s[1024];
    s[t] = acc;
    __syncthreads();
    #pragma unroll
    for (int step = 512; step > 0; step >>= 1) {
        if (t < step) s[t] += s[t + step];
        __syncthreads();
    }
    if (t == 0) out[0] = s[0] * (1.0f / (float)B_N);
}

extern "C" void kernel_launch(void* const* d_in, const int* in_sizes, int n_in,
                              void* d_out, int out_size, void* d_ws, size_t ws_size,
                              hipStream_t stream) {
    const float* x = (const float*)d_in[0];
    float* out = (float*)d_out;
    char* ws = (char*)d_ws;

    unsigned int* xq = (unsigned int*)ws;                              // 8 MB fp8
    unsigned long long* rowmax = (unsigned long long*)(ws + 8388608);  // 64 KB

    knorm<<<B_N * V_N, 256, 0, stream>>>(x, xq, rowmax);
    kargmax<<<dim3(NTRI, V_N), 256, 0, stream>>>((const unsigned char*)xq, rowmax);
    kloss<<<1, 1024, 0, stream>>>(rowmax, out);
}

// Round 22
// 55.927 us; speedup vs baseline: 1.4350x; 1.4350x over previous
//
#include <hip/hip_runtime.h>
#include <hip/hip_bf16.h>
#include <stdint.h>

#define B_N 4096
#define V_N 2
#define D_N 1024
#define EPS 1e-8f
#define NT 32                // 4096/128 tiles per dim
#define NTRI (NT*(NT+1)/2)   // 528 = 8*66 -> clean XCD chunking
#define NSTEP 8              // K-steps of BK=128 fp8

typedef __attribute__((ext_vector_type(4))) float f32x4;
typedef __attribute__((ext_vector_type(2))) long long ll2;

__device__ __forceinline__ unsigned int f2mono(float f) {
    unsigned int u = __float_as_uint(f);
    return (u & 0x80000000u) ? ~u : (u | 0x80000000u);
}

__device__ __forceinline__ float mono2f(unsigned int m) {
    unsigned int u = (m & 0x80000000u) ? (m ^ 0x80000000u) : ~m;
    return __uint_as_float(u);
}

__device__ __forceinline__ unsigned long long shfl_xor_u64(unsigned long long v, int m) {
    unsigned int lo = (unsigned int)v, hi = (unsigned int)(v >> 32);
    lo = __shfl_xor(lo, m, 64);
    hi = __shfl_xor(hi, m, 64);
    return ((unsigned long long)hi << 32) | lo;
}

#define GLD16(src, dst) __builtin_amdgcn_global_load_lds(                      \
    (const __attribute__((address_space(1))) unsigned int*)(src),             \
    (__attribute__((address_space(3))) unsigned int*)(dst), 16, 0, 0)

// -------- Kernel 1: L2-normalize, emit OCP fp8 e4m3 (V,B,D) ---------------
// Also zeroes this block's rowmax slot (replaces the memset dispatch).
__global__ __launch_bounds__(256) void knorm(const float* __restrict__ x,
                                             unsigned int* __restrict__ xq,
                                             unsigned long long* __restrict__ rowmax) {
    int r = blockIdx.x;            // r = b*V + v  (input rows are contiguous)
    int b = r >> 1, v = r & 1;
    if (threadIdx.x == 0) rowmax[r] = 0ull;
    const float* row = x + (size_t)r * D_N;
    int t = threadIdx.x;
    float4 val = reinterpret_cast<const float4*>(row)[t];
    float ss = val.x * val.x + val.y * val.y + val.z * val.z + val.w * val.w;
    #pragma unroll
    for (int s = 32; s > 0; s >>= 1) ss += __shfl_xor(ss, s, 64);
    __shared__ float wsum[4];
    if ((t & 63) == 0) wsum[t >> 6] = ss;
    __syncthreads();
    float tot = wsum[0] + wsum[1] + wsum[2] + wsum[3];
    float rn = 1.0f / sqrtf(tot + EPS);
    int pk = 0;
    pk = __builtin_amdgcn_cvt_pk_fp8_f32(val.x * rn, val.y * rn, pk, false);
    pk = __builtin_amdgcn_cvt_pk_fp8_f32(val.z * rn, val.w * rn, pk, true);
    xq[((size_t)v * B_N + b) * 256 + t] = (unsigned int)pk;
}

// ------- Kernel 2: per-view X·X^T, row-wise argmax, fp8 MFMA ---------------
// Measured-knee config (r19, 55.2 us total): BK=128 single-buffer, per step
// 8 GLD16/wave in flight (max MLP per stall window) and only 8 windows.
// 128x128 tile, 4 waves, acc[4][4] (VGPR 64 -> 4 blocks/CU co-residency,
// which hides the per-window stall -- every structure that lost occupancy
// regressed: r16/r17 big wave-tiles, r20 64KB dbuf, r21 reg-staging spill).
// Swizzle f(row)=row&7: write source chunk (l&7)^(l>>3); read physical slot
// (h*4+g)^(row&7) -> PMC-verified 0 bank conflicts. Two MFMA rounds per
// step (slots {g}, {4+g}); A/B identically permuted -> exact dot.
__global__ __launch_bounds__(256, 4) void kargmax(const unsigned char* __restrict__ xq,
                                                  unsigned long long* __restrict__ rowmax) {
    __shared__ unsigned char lA[16384];   // 128 rows x 128 B
    __shared__ unsigned char lB[16384];
    const int v = blockIdx.y;
    // T1: chunked XCD swizzle (bijective: 528 = 8*66)
    const int bx = (blockIdx.x & 7) * (NTRI / 8) + (blockIdx.x >> 3);
    int ti = (int)((sqrtf(8.f * (float)bx + 1.f) - 1.f) * 0.5f);
    while ((ti + 1) * (ti + 2) / 2 <= bx) ti++;
    while (ti * (ti + 1) / 2 > bx) ti--;
    const int tj = bx - ti * (ti + 1) / 2;
    const int i0 = ti * 128;
    const int j0 = tj * 128;
    const bool diag = (ti == tj);
    const unsigned char* Xv = xq + (size_t)v * B_N * D_N;

    const int tid = threadIdx.x;
    const int wid = tid >> 6, lane = tid & 63;
    const int wr = wid >> 1, wc = wid & 1;

    f32x4 acc[4][4];
    #pragma unroll
    for (int m = 0; m < 4; m++)
        #pragma unroll
        for (int n = 0; n < 4; n++) acc[m][n] = (f32x4){0.f, 0.f, 0.f, 0.f};

    // Write side: GLD16 k covers rows wid*32 + k*8 + (l>>3), physical 16B
    // slot l&7; source chunk = (l&7) ^ f(row), f(row) = row&7 = (l>>3).
    const int csw = ((lane & 7) ^ (lane >> 3)) * 16;
    const unsigned char* pA = Xv + (size_t)(i0 + wid * 32 + (lane >> 3)) * D_N + csw;
    const unsigned char* pB = Xv + (size_t)(j0 + wid * 32 + (lane >> 3)) * D_N + csw;

    // Read side: round h, group g = lane>>4 reads logical slot h*4+g of row
    // (row%16 = lane&15): physical = (h*4+g) ^ (row&7).
    const int rs0 = (((lane >> 4) ^ (lane & 7))) * 16;
    const int rs1 = rs0 ^ 64;

#define STAGE(t) do {                                                          \
    const unsigned char* _a = pA + (t) * 128;                                  \
    const unsigned char* _b = pB + (t) * 128;                                  \
    unsigned char* _dA = lA + wid * 4096;                                      \
    unsigned char* _dB = lB + wid * 4096;                                      \
    GLD16(_a,          _dA);                                                   \
    GLD16(_a +  8192,  _dA + 1024);                                            \
    GLD16(_a + 16384,  _dA + 2048);                                            \
    GLD16(_a + 24576,  _dA + 3072);                                            \
    GLD16(_b,          _dB);                                                   \
    GLD16(_b +  8192,  _dB + 1024);                                            \
    GLD16(_b + 16384,  _dB + 2048);                                            \
    GLD16(_b + 24576,  _dB + 3072);                                            \
} while (0)

#define CROUND(rs) do {                                                        \
    ll2 a[4], b[4];                                                            \
    _Pragma("unroll")                                                          \
    for (int m = 0; m < 4; m++)                                                \
        a[m] = *reinterpret_cast<const ll2*>(                                  \
            lA + (wr * 64 + m * 16 + (lane & 15)) * 128 + (rs));               \
    _Pragma("unroll")                                                          \
    for (int n = 0; n < 4; n++)                                                \
        b[n] = *reinterpret_cast<const ll2*>(                                  \
            lB + (wc * 64 + n * 16 + (lane & 15)) * 128 + (rs));               \
    __builtin_amdgcn_s_setprio(1);                                             \
    _Pragma("unroll")                                                          \
    for (int m = 0; m < 4; m++)                                                \
        _Pragma("unroll")                                                      \
        for (int n = 0; n < 4; n++) {                                          \
            acc[m][n] = __builtin_amdgcn_mfma_f32_16x16x32_fp8_fp8(            \
                a[m][0], b[n][0], acc[m][n], 0, 0, 0);                         \
            acc[m][n] = __builtin_amdgcn_mfma_f32_16x16x32_fp8_fp8(            \
                a[m][1], b[n][1], acc[m][n], 0, 0, 0);                         \
        }                                                                      \
    __builtin_amdgcn_s_setprio(0);                                             \
} while (0)

    // ---- Main loop: 8 steps, single buffer ----
    #pragma unroll 1
    for (int t = 0; t < NSTEP; ++t) {
        STAGE(t);
        asm volatile("s_waitcnt vmcnt(0)" ::: "memory");   // tile t landed
        __builtin_amdgcn_s_barrier();
        CROUND(rs0);           // logical slots g   (K bytes 0..63 of window)
        CROUND(rs1);           // logical slots 4+g (K bytes 64..127)
        __builtin_amdgcn_s_barrier();   // all reads retired before restage
    }

    // ---- Epilogue A: row side (rows i0.., cols j0..) ----
    // C/D layout: col = lane&15, row = (lane>>4)*4 + reg  [m89/m91-verified]
    #pragma unroll
    for (int m = 0; m < 4; m++) {
        int rbase = i0 + wr * 64 + m * 16;
        #pragma unroll
        for (int j = 0; j < 4; j++) {
            int grow = rbase + (lane >> 4) * 4 + j;
            unsigned long long best = 0ull;
            #pragma unroll
            for (int n = 0; n < 4; n++) {
                int gcol = j0 + wc * 64 + n * 16 + (lane & 15);
                float vdot = acc[m][n][j];
                unsigned long long p = (grow == gcol)
                    ? 0ull
                    : ((unsigned long long)f2mono(vdot) << 32) | (unsigned int)(~(unsigned int)gcol);
                best = p > best ? p : best;
            }
            #pragma unroll
            for (int s = 1; s < 16; s <<= 1) {
                unsigned long long o = shfl_xor_u64(best, s);
                best = o > best ? o : best;
            }
            if ((lane & 15) == 0)
                atomicMax(&rowmax[(size_t)v * B_N + grow], best);
        }
    }

    // ---- Epilogue B: transposed side (rows j0.., cols i0..), off-diag only ----
    if (!diag) {
        #pragma unroll
        for (int n = 0; n < 4; n++) {
            int growT = j0 + wc * 64 + n * 16 + (lane & 15);   // C column = transposed row
            unsigned long long best = 0ull;
            #pragma unroll
            for (int m = 0; m < 4; m++) {
                int ibase = i0 + wr * 64 + m * 16 + (lane >> 4) * 4;
                #pragma unroll
                for (int j = 0; j < 4; j++) {
                    int gi = ibase + j;                        // C row = transposed col
                    float vdot = acc[m][n][j];
                    unsigned long long p =
                        ((unsigned long long)f2mono(vdot) << 32) | (unsigned int)(~(unsigned int)gi);
                    best = p > best ? p : best;
                }
            }
            #pragma unroll
            for (int s = 16; s < 64; s <<= 1) {
                unsigned long long o = shfl_xor_u64(best, s);
                best = o > best ? o : best;
            }
            if (lane < 16)
                atomicMax(&rowmax[(size_t)v * B_N + growT], best);
        }
    }
#undef STAGE
#undef CROUND
}

// --- Kernel 3: decode loss directly from packed keys, reduce to scalar -----
// Key = (f2mono(dot) << 32) | ~col ; rows are unit-norm, dist = sqrt(2-2*dot).
__global__ __launch_bounds__(1024) void kloss(const unsigned long long* __restrict__ rowmax,
                                              float* __restrict__ out) {
    int t = threadIdx.x;
    float acc = 0.f;
    #pragma unroll
    for (int i = t; i < V_N * B_N; i += 1024) {
        unsigned long long k = rowmax[i];
        float dot = mono2f((unsigned int)(k >> 32));
        float d2 = fmaxf(2.0f - 2.0f * dot, 0.0f);
        acc += -logf(sqrtf(d2) + EPS);
    }
    __shared__ float s[1024];
    s[t] = acc;
    __syncthreads();
    #pragma unroll
    for (int step = 512; step > 0; step >>= 1) {
        if (t < step) s[t] += s[t + step];
        __syncthreads();
    }
    if (t == 0) out[0] = s[0] * (1.0f / (float)B_N);
}

extern "C" void kernel_launch(void* const* d_in, const int* in_sizes, int n_in,
                              void* d_out, int out_size, void* d_ws, size_t ws_size,
                              hipStream_t stream) {
    const float* x = (const float*)d_in[0];
    float* out = (float*)d_out;
    char* ws = (char*)d_ws;

    unsigned int* xq = (unsigned int*)ws;                              // 8 MB fp8
    unsigned long long* rowmax = (unsigned long long*)(ws + 8388608);  // 64 KB

    knorm<<<B_N * V_N, 256, 0, stream>>>(x, xq, rowmax);
    kargmax<<<dim3(NTRI, V_N), 256, 0, stream>>>((const unsigned char*)xq, rowmax);
    kloss<<<1, 1024, 0, stream>>>(rowmax, out);
}